// Round 4
// baseline (74.440 us; speedup 1.0000x reference)
//
#include <hip/hip_runtime.h>

typedef float f4v __attribute__((ext_vector_type(4)));

#define BLOCK 256
#define VEC_T 192   // tids 0..191: one output float4 of each vec3 stream (P,V,B)
                    // tids 192..255: one output float4 of each scalar stream (W,BV,VR)

static __device__ __forceinline__ f4v ntload4(const f4v* p) {
    return __builtin_nontemporal_load(p);
}
static __device__ __forceinline__ void ntstore4(f4v v, f4v* p) {
    __builtin_nontemporal_store(v, p);
}

// Full per-ray physics. Outputs already masked where needed by caller.
static __device__ __forceinline__ void ray_calc(
    float px, float py, float pz,
    float vx, float vy, float vz,
    float lam,
    float& Xx, float& Xy, float& Xz,
    float& ox, float& oy, float& oz,
    bool& both, bool& tir)
{
    // oc = P - center, center=(0,0,60), R^2=2500
    const float ocx = px, ocy = py, ocz = pz - 60.0f;
    const float b = ocx*vx + ocy*vy + ocz*vz;
    const float c = ocx*ocx + ocy*ocy + ocz*ocz - 2500.0f;
    const float disc = b*b - c;
    const bool valid = (disc >= 0.0f);
    const float sq = valid ? __builtin_amdgcn_sqrtf(disc) : 0.0f;
    const float tt = -b - sq;
    Xx = px + tt*vx;
    Xy = py + tt*vy;
    Xz = pz + tt*vz;
    const float invR = 1.0f / 50.0f;
    const float nx = Xx*invR, ny = Xy*invR, nz = (Xz - 60.0f)*invR;
    const float dvn = vx*nx + vy*ny + vz*nz;
    const float s = (dvn > 0.0f) ? -1.0f : 1.0f;
    const float nfx = s*nx, nfy = s*ny, nfz = s*nz;
    const float cos_i = -(vx*nfx + vy*nfy + vz*nfz);
    const float inv_l2 = __builtin_amdgcn_rcpf(lam*lam);
    const float n2 = 1.5046f + 0.0042f*inv_l2;   // n1 = 1.0
    const float eta = __builtin_amdgcn_rcpf(n2);
    const float sin2 = eta*eta*(1.0f - cos_i*cos_i);
    tir = (sin2 > 1.0f);
    const float cos_t = tir ? 0.0f : __builtin_amdgcn_sqrtf(1.0f - sin2);
    const float k = eta*cos_i - cos_t;
    if (tir) {
        ox = vx + 2.0f*cos_i*nfx;
        oy = vy + 2.0f*cos_i*nfy;
        oz = vz + 2.0f*cos_i*nfz;
    } else {
        ox = eta*vx + k*nfx;
        oy = eta*vy + k*nfy;
        oz = eta*vz + k*nfz;
    }
    both = valid && !tir;
}

__global__ __launch_bounds__(BLOCK, 6) void refract_stream_kernel(
    const f4v* __restrict__ P4,
    const f4v* __restrict__ V4,
    const f4v* __restrict__ B4,
    const float* __restrict__ W,
    const f4v* __restrict__ W4,
    f4v* __restrict__ outP,
    f4v* __restrict__ outV,
    f4v* __restrict__ outB,
    f4v* __restrict__ outW,
    f4v* __restrict__ outBV,
    f4v* __restrict__ outVR,
    int NV4)            // total float4s per vec3 stream = 3N/4
{
    const int tid = threadIdx.x;
    const int blk = blockIdx.x;

    if (tid < VEC_T) {
        // ---- vec role: output float4 g of P, V, B -----------------------
        const int g = blk * VEC_T + tid;
        const int m = g % 3;                      // 4g mod 3 == g mod 3
        const unsigned r0 = (4u * (unsigned)g) / 3u;

        const int gm1 = (g > 0) ? g - 1 : 0;          // A unused when m==0 (g==0 has m==0)
        const int gp1 = (g < NV4 - 1) ? g + 1 : g;    // C unused when m==2 (last g has m==2)

        const f4v pA = P4[gm1], pB = P4[g], pC = P4[gp1];
        const f4v vA = V4[gm1], vB = V4[g], vC = V4[gp1];
        const f4v b4 = ntload4(&B4[g]);
        const float w0 = W[r0], w1 = W[r0 + 1];

        // buf[0..11] = {A,B,C}; ray0 = buf[4-m .. 6-m], ray1 = buf[7-m .. 9-m]
        const bool m0 = (m == 0), m1 = (m == 1);
        const float p0x = m0 ? pB.x : (m1 ? pA.w : pA.z);
        const float p0y = m0 ? pB.y : (m1 ? pB.x : pA.w);
        const float p0z = m0 ? pB.z : (m1 ? pB.y : pB.x);
        const float p1x = m0 ? pB.w : (m1 ? pB.z : pB.y);
        const float p1y = m0 ? pC.x : (m1 ? pB.w : pB.z);
        const float p1z = m0 ? pC.y : (m1 ? pC.x : pB.w);
        const float v0x = m0 ? vB.x : (m1 ? vA.w : vA.z);
        const float v0y = m0 ? vB.y : (m1 ? vB.x : vA.w);
        const float v0z = m0 ? vB.z : (m1 ? vB.y : vB.x);
        const float v1x = m0 ? vB.w : (m1 ? vB.z : vB.y);
        const float v1y = m0 ? vC.x : (m1 ? vB.w : vB.z);
        const float v1z = m0 ? vC.y : (m1 ? vC.x : vB.w);

        float X0x,X0y,X0z, o0x,o0y,o0z; bool both0, tir0;
        ray_calc(p0x,p0y,p0z, v0x,v0y,v0z, w0, X0x,X0y,X0z, o0x,o0y,o0z, both0, tir0);
        float X1x,X1y,X1z, o1x,o1y,o1z; bool both1, tir1;
        ray_calc(p1x,p1y,p1z, v1x,v1y,v1z, w1, X1x,X1y,X1z, o1x,o1y,o1z, both1, tir1);

        // mask
        const float X0mx = both0 ? X0x : 0.0f, X0my = both0 ? X0y : 0.0f, X0mz = both0 ? X0z : 0.0f;
        const float X1mx = both1 ? X1x : 0.0f, X1my = both1 ? X1y : 0.0f, X1mz = both1 ? X1z : 0.0f;
        const float o0mx = both0 ? o0x : 0.0f, o0my = both0 ? o0y : 0.0f, o0mz = both0 ? o0z : 0.0f;
        const float o1mx = both1 ? o1x : 0.0f, o1my = both1 ? o1y : 0.0f, o1mz = both1 ? o1z : 0.0f;
        const float bv0 = both0 ? 1.0f : 0.0f, bv1 = both1 ? 1.0f : 0.0f;

        // assemble output float4s:
        // m=0: [r0.x r0.y r0.z r1.x]  m=1: [r0.y r0.z r1.x r1.y]  m=2: [r0.z r1.x r1.y r1.z]
        f4v oP, oV, oB;
        oP.x = m0 ? X0mx : (m1 ? X0my : X0mz);
        oP.y = m0 ? X0my : (m1 ? X0mz : X1mx);
        oP.z = m0 ? X0mz : (m1 ? X1mx : X1my);
        oP.w = m0 ? X1mx : (m1 ? X1my : X1mz);
        oV.x = m0 ? o0mx : (m1 ? o0my : o0mz);
        oV.y = m0 ? o0my : (m1 ? o0mz : o1mx);
        oV.z = m0 ? o0mz : (m1 ? o1mx : o1my);
        oV.w = m0 ? o1mx : (m1 ? o1my : o1mz);
        oB.x = b4.x * bv0;                         // comp.x always ray r0
        oB.y = b4.y * ((m == 2) ? bv1 : bv0);
        oB.z = b4.z * (m0 ? bv0 : bv1);
        oB.w = b4.w * bv1;                         // comp.w always ray r1

        ntstore4(oP, &outP[g]);
        ntstore4(oV, &outV[g]);
        ntstore4(oB, &outB[g]);
    } else {
        // ---- scalar role: output float4 s of W, BV, VR ------------------
        const int s = blk * (BLOCK - VEC_T) + (tid - VEC_T);
        const f4v pa = P4[3*s], pb = P4[3*s+1], pc = P4[3*s+2];
        const f4v va = V4[3*s], vb = V4[3*s+1], vc = V4[3*s+2];
        const f4v l4 = W4[s];

        f4v oW, oBV, oVR;
        {
            float Xx,Xy,Xz, ox,oy,oz; bool both, tir;
            ray_calc(pa.x,pa.y,pa.z, va.x,va.y,va.z, l4.x, Xx,Xy,Xz, ox,oy,oz, both, tir);
            oW.x = both ? l4.x : 0.0f; oBV.x = both ? 1.0f : 0.0f; oVR.x = tir ? 0.0f : 1.0f;
        }
        {
            float Xx,Xy,Xz, ox,oy,oz; bool both, tir;
            ray_calc(pa.w,pb.x,pb.y, va.w,vb.x,vb.y, l4.y, Xx,Xy,Xz, ox,oy,oz, both, tir);
            oW.y = both ? l4.y : 0.0f; oBV.y = both ? 1.0f : 0.0f; oVR.y = tir ? 0.0f : 1.0f;
        }
        {
            float Xx,Xy,Xz, ox,oy,oz; bool both, tir;
            ray_calc(pb.z,pb.w,pc.x, vb.z,vb.w,vc.x, l4.z, Xx,Xy,Xz, ox,oy,oz, both, tir);
            oW.z = both ? l4.z : 0.0f; oBV.z = both ? 1.0f : 0.0f; oVR.z = tir ? 0.0f : 1.0f;
        }
        {
            float Xx,Xy,Xz, ox,oy,oz; bool both, tir;
            ray_calc(pc.y,pc.z,pc.w, vc.y,vc.z,vc.w, l4.w, Xx,Xy,Xz, ox,oy,oz, both, tir);
            oW.w = both ? l4.w : 0.0f; oBV.w = both ? 1.0f : 0.0f; oVR.w = tir ? 0.0f : 1.0f;
        }

        ntstore4(oW,  &outW [s]);
        ntstore4(oBV, &outBV[s]);
        ntstore4(oVR, &outVR[s]);
    }
}

extern "C" void kernel_launch(void* const* d_in, const int* in_sizes, int n_in,
                              void* d_out, int out_size, void* d_ws, size_t ws_size,
                              hipStream_t stream) {
    const int N = in_sizes[3];           // rays_wavelength element count
    const int NV4 = (N / 4) * 3;         // float4s per vec3 stream
    const int nBlocks = N / BLOCK;       // each block: 192 vec-f4 + 64 scalar-f4 = 256 rays

    const f4v*  P4 = (const f4v*)d_in[0];
    const f4v*  V4 = (const f4v*)d_in[1];
    const f4v*  B4 = (const f4v*)d_in[2];
    const float* W = (const float*)d_in[3];
    const f4v*  W4 = (const f4v*)d_in[3];

    float* out = (float*)d_out;
    f4v* outP  = (f4v*)(out + (size_t)0  * N);
    f4v* outV  = (f4v*)(out + (size_t)3  * N);
    f4v* outB  = (f4v*)(out + (size_t)6  * N);
    f4v* outW  = (f4v*)(out + (size_t)9  * N);
    f4v* outBV = (f4v*)(out + (size_t)10 * N);
    f4v* outVR = (f4v*)(out + (size_t)11 * N);

    refract_stream_kernel<<<nBlocks, BLOCK, 0, stream>>>(
        P4, V4, B4, W, W4, outP, outV, outB, outW, outBV, outVR, NV4);
}

// Round 5
// 58.318 us; speedup vs baseline: 1.2764x; 1.2764x over previous
//
#include <hip/hip_runtime.h>

typedef float f4v __attribute__((ext_vector_type(4)));

#define BLOCK 256
#define RPB   1024          // rays per block (= 4 * BLOCK)
#define V4PB  768           // float4s per vec3 stream per block (RPB*3/4)
#define S4PB  256           // float4s per scalar stream per block (RPB/4)

static __device__ __forceinline__ void ntstore4(f4v v, f4v* p) {
    __builtin_nontemporal_store(v, p);
}

// Full per-ray physics; returns pre-masked position/direction + mask floats.
static __device__ __forceinline__ void ray_calc(
    float px, float py, float pz,
    float vx, float vy, float vz,
    float lam,
    float& Xx, float& Xy, float& Xz,
    float& ox, float& oy, float& oz,
    float& wm, float& bvm, float& vrm)
{
    // oc = P - center, center=(0,0,60), R^2=2500
    const float ocx = px, ocy = py, ocz = pz - 60.0f;
    const float b = ocx*vx + ocy*vy + ocz*vz;
    const float c = ocx*ocx + ocy*ocy + ocz*ocz - 2500.0f;
    const float disc = b*b - c;
    const bool valid = (disc >= 0.0f);
    const float sq = valid ? __builtin_amdgcn_sqrtf(disc) : 0.0f;
    const float tt = -b - sq;
    float Xxu = px + tt*vx;
    float Xyu = py + tt*vy;
    float Xzu = pz + tt*vz;
    const float invR = 1.0f / 50.0f;
    const float nx = Xxu*invR, ny = Xyu*invR, nz = (Xzu - 60.0f)*invR;
    const float dvn = vx*nx + vy*ny + vz*nz;
    const float s = (dvn > 0.0f) ? -1.0f : 1.0f;
    const float nfx = s*nx, nfy = s*ny, nfz = s*nz;
    const float cos_i = -(vx*nfx + vy*nfy + vz*nfz);
    const float inv_l2 = __builtin_amdgcn_rcpf(lam*lam);
    const float n2 = 1.5046f + 0.0042f*inv_l2;   // n1 = 1.0
    const float eta = __builtin_amdgcn_rcpf(n2);
    const float sin2 = eta*eta*(1.0f - cos_i*cos_i);
    const bool tir = (sin2 > 1.0f);
    const float cos_t = tir ? 0.0f : __builtin_amdgcn_sqrtf(1.0f - sin2);
    const float k = eta*cos_i - cos_t;
    float oxu, oyu, ozu;
    if (tir) {
        oxu = vx + 2.0f*cos_i*nfx;
        oyu = vy + 2.0f*cos_i*nfy;
        ozu = vz + 2.0f*cos_i*nfz;
    } else {
        oxu = eta*vx + k*nfx;
        oyu = eta*vy + k*nfy;
        ozu = eta*vz + k*nfz;
    }
    const bool both = valid && !tir;
    const float m = both ? 1.0f : 0.0f;
    Xx = both ? Xxu : 0.0f;  Xy = both ? Xyu : 0.0f;  Xz = both ? Xzu : 0.0f;
    ox = both ? oxu : 0.0f;  oy = both ? oyu : 0.0f;  oz = both ? ozu : 0.0f;
    wm  = both ? lam : 0.0f;
    bvm = m;
    vrm = tir ? 0.0f : 1.0f;
}

__global__ __launch_bounds__(BLOCK, 5) void refract_ob_kernel(
    const f4v* __restrict__ P4,
    const f4v* __restrict__ V4,
    const f4v* __restrict__ B4,
    const f4v* __restrict__ W4,
    f4v* __restrict__ outP,
    f4v* __restrict__ outV,
    f4v* __restrict__ outB,
    f4v* __restrict__ outW,
    f4v* __restrict__ outBV,
    f4v* __restrict__ outVR)
{
    __shared__ f4v sX4[V4PB];   // 12 KB — masked X, output-f4 layout
    __shared__ f4v sO4[V4PB];   // 12 KB — masked out_dir, output-f4 layout
    __shared__ f4v sM4[S4PB];   //  4 KB — both_valid masks, ray-indexed floats

    const int t   = threadIdx.x;
    const int blk = blockIdx.x;
    const int v4  = blk * V4PB;
    const int s4  = blk * S4PB;

    // ---- Phase 1: loads -------------------------------------------------
    // P,V: per-thread 3 consecutive f4s (rays 4t..4t+3) — stride-48B across
    // lanes; reads carry no RFO penalty, L1/L2 merge the sector overlap.
    const f4v pA = P4[v4 + 3*t + 0], pB = P4[v4 + 3*t + 1], pC = P4[v4 + 3*t + 2];
    const f4v vA = V4[v4 + 3*t + 0], vB = V4[v4 + 3*t + 1], vC = V4[v4 + 3*t + 2];
    // W: coalesced f4 (4 wavelengths for this thread's rays).
    const f4v w4 = W4[s4 + t];
    // B: coalesced f4s held in registers for phase 3 (pure passthrough).
    const f4v b0 = B4[v4 + 0*BLOCK + t];
    const f4v b1 = B4[v4 + 1*BLOCK + t];
    const f4v b2 = B4[v4 + 2*BLOCK + t];

    // ---- Phase 2: compute 4 thread-local rays (static component maps) ---
    float X0x,X0y,X0z,o0x,o0y,o0z,w0,m0,r0;
    float X1x,X1y,X1z,o1x,o1y,o1z,w1,m1,r1;
    float X2x,X2y,X2z,o2x,o2y,o2z,w2,m2,r2;
    float X3x,X3y,X3z,o3x,o3y,o3z,w3,m3,r3;
    ray_calc(pA.x,pA.y,pA.z, vA.x,vA.y,vA.z, w4.x, X0x,X0y,X0z, o0x,o0y,o0z, w0,m0,r0);
    ray_calc(pA.w,pB.x,pB.y, vA.w,vB.x,vB.y, w4.y, X1x,X1y,X1z, o1x,o1y,o1z, w1,m1,r1);
    ray_calc(pB.z,pB.w,pC.x, vB.z,vB.w,vC.x, w4.z, X2x,X2y,X2z, o2x,o2y,o2z, w2,m2,r2);
    ray_calc(pC.y,pC.z,pC.w, vC.y,vC.z,vC.w, w4.w, X3x,X3y,X3z, o3x,o3y,o3z, w3,m3,r3);

    // Scalar streams: naturally f4-aligned — store NOW (before barrier).
    f4v oW, oBV, oVR;
    oW.x  = w0; oW.y  = w1; oW.z  = w2; oW.w  = w3;
    oBV.x = m0; oBV.y = m1; oBV.z = m2; oBV.w = m3;
    oVR.x = r0; oVR.y = r1; oVR.z = r2; oVR.w = r3;
    ntstore4(oW,  &outW [s4 + t]);
    ntstore4(oBV, &outBV[s4 + t]);
    ntstore4(oVR, &outVR[s4 + t]);

    // Stage X / out_dir into LDS in output-f4 layout (b128 writes at 48B
    // lane stride: lanes 0..7 touch all 32 banks exactly once — conflict-free).
    f4v a;
    a.x=X0x; a.y=X0y; a.z=X0z; a.w=X1x;  sX4[3*t+0] = a;
    a.x=X1y; a.y=X1z; a.z=X2x; a.w=X2y;  sX4[3*t+1] = a;
    a.x=X2z; a.y=X3x; a.z=X3y; a.w=X3z;  sX4[3*t+2] = a;
    a.x=o0x; a.y=o0y; a.z=o0z; a.w=o1x;  sO4[3*t+0] = a;
    a.x=o1y; a.y=o1z; a.z=o2x; a.w=o2y;  sO4[3*t+1] = a;
    a.x=o2z; a.y=o3x; a.z=o3y; a.w=o3z;  sO4[3*t+2] = a;
    a.x=m0; a.y=m1; a.z=m2; a.w=m3;      sM4[t] = a;

    __syncthreads();

    // ---- Phase 3: fully coalesced nt stores ----------------------------
    const float* sMf = (const float*)sM4;
    #pragma unroll
    for (int k = 0; k < 3; ++k) {
        const int i = k*BLOCK + t;
        ntstore4(sX4[i], &outP[v4 + i]);
        ntstore4(sO4[i], &outV[v4 + i]);
        f4v bm = (k == 0) ? b0 : ((k == 1) ? b1 : b2);
        const unsigned f = 4u * (unsigned)i;
        bm.x *= sMf[(f + 0u) / 3u];
        bm.y *= sMf[(f + 1u) / 3u];
        bm.z *= sMf[(f + 2u) / 3u];
        bm.w *= sMf[(f + 3u) / 3u];
        ntstore4(bm, &outB[v4 + i]);
    }
}

extern "C" void kernel_launch(void* const* d_in, const int* in_sizes, int n_in,
                              void* d_out, int out_size, void* d_ws, size_t ws_size,
                              hipStream_t stream) {
    const int N = in_sizes[3];           // rays_wavelength element count
    const int nBlocks = N / RPB;

    const f4v* P4 = (const f4v*)d_in[0];
    const f4v* V4 = (const f4v*)d_in[1];
    const f4v* B4 = (const f4v*)d_in[2];
    const f4v* W4 = (const f4v*)d_in[3];

    float* out = (float*)d_out;
    f4v* outP  = (f4v*)(out + (size_t)0  * N);
    f4v* outV  = (f4v*)(out + (size_t)3  * N);
    f4v* outB  = (f4v*)(out + (size_t)6  * N);
    f4v* outW  = (f4v*)(out + (size_t)9  * N);
    f4v* outBV = (f4v*)(out + (size_t)10 * N);
    f4v* outVR = (f4v*)(out + (size_t)11 * N);

    refract_ob_kernel<<<nBlocks, BLOCK, 0, stream>>>(
        P4, V4, B4, W4, outP, outV, outB, outW, outBV, outVR);
}